// Round 6
// baseline (2123.443 us; speedup 1.0000x reference)
//
#include <hip/hip_runtime.h>
#include <hip/hip_bf16.h>

// DHHT round 6: phi_kernel re-grid (the 123us/13%-occupancy latency-starved
// dispatch). K mode: 8 rows/block (grid CH/8), Q mode: 2 rows/block (grid CH/2).
// All else carried from round 5 (1766us, passed, absmax 0.031).
// W2T bf16 [256][4096]: cols 0..2047 = W2u (ktv@F^T), 2048..4095 = G.

#define EPSF 1e-6f

typedef __attribute__((ext_vector_type(8))) short bf16x8;
typedef __attribute__((ext_vector_type(8))) unsigned short u16x8;
typedef __attribute__((ext_vector_type(4))) float f32x4;
typedef float f32x4a __attribute__((ext_vector_type(4), aligned(4)));

__device__ __forceinline__ float b2f(unsigned short u) {
    union { unsigned int i; float f; } c;
    c.i = ((unsigned int)u) << 16;
    return c.f;
}
__device__ __forceinline__ unsigned short f2b(float f) {
    __hip_bfloat16 h = __float2bfloat16(f);
    union { __hip_bfloat16 h; unsigned short u; } c;
    c.h = h;
    return c.u;
}

__global__ void zero_kernel(float* __restrict__ p, int n) {
    int i = blockIdx.x * 256 + threadIdx.x;
    if (i < n) p[i] = 0.f;
}

// ---------------- weight convert: Wbf [6144][288] bf16 + biasAll[6144] ----------------
__global__ __launch_bounds__(256) void wconv_kernel(
    const float* __restrict__ Wq, const float* __restrict__ Wk, const float* __restrict__ Wv,
    const float* __restrict__ Bq, const float* __restrict__ Bk, const float* __restrict__ Bv,
    unsigned short* __restrict__ Wbf, float* __restrict__ biasAll)
{
    const int t = threadIdx.x;
    const int b = blockIdx.x;
    if (b < 6144) {
        const int mat = b >> 11, lr = b & 2047;
        const float* Ws = (mat == 0 ? Wq : mat == 1 ? Wk : Wv) + (size_t)lr * 257;
        Wbf[(size_t)b * 288 + t] = f2b(Ws[t]);
        if (t < 32) {
            float v = (t == 0) ? Ws[256] : 0.f;
            Wbf[(size_t)b * 288 + 256 + t] = f2b(v);
        }
    } else {
        const int e = (b - 6144) * 256 + t;
        const int mat = e >> 11, r = e & 2047;
        biasAll[e] = (mat == 0 ? Bq : mat == 1 ? Bk : Bv)[r];
    }
}

// ---------------- projection MFMA GEMM: X fp32 [rows][257] @ Wbf[cols][288]^T ----------------
__global__ __launch_bounds__(256) void proj_mfma(
    const float* __restrict__ X,
    const unsigned short* __restrict__ Wbase,
    const float* __restrict__ biasBase,
    unsigned short* __restrict__ outA,
    unsigned short* __restrict__ outB,
    int splitCol)
{
    __shared__ __align__(16) unsigned short lA[128 * 40];
    __shared__ __align__(16) unsigned short lB[128 * 40];
    const int t = threadIdx.x;
    const int m0 = blockIdx.x * 128;
    const int c0 = blockIdx.y * 128;
    const int lane = t & 63, w = t >> 6;
    const int wm = (w >> 1) * 64, wn = (w & 1) * 64;
    const int l15 = lane & 15, q = lane >> 4;

    f32x4 acc[4][4] = {};

    for (int ks = 0; ks < 9; ++ks) {
        const int k0 = ks * 32;
        if (ks < 8) {
#pragma unroll
            for (int qq = 0; qq < 4; ++qq) {
                const int e = t + qq * 256;
                const int row = e >> 3, kg = (e & 7) * 4;
                f32x4a xv = *(const f32x4a*)(X + (size_t)(m0 + row) * 257 + k0 + kg);
                unsigned short* d = &lA[row * 40 + kg];
                d[0] = f2b(xv[0]); d[1] = f2b(xv[1]);
                d[2] = f2b(xv[2]); d[3] = f2b(xv[3]);
            }
        } else {
#pragma unroll
            for (int qq = 0; qq < 2; ++qq) {
                const int e = t + qq * 256;
                const int row = e >> 2, part = e & 3;
                u16x8 z = {};
                if (part == 0) z[0] = f2b(X[(size_t)(m0 + row) * 257 + 256]);
                *(u16x8*)(&lA[row * 40 + part * 8]) = z;
            }
        }
#pragma unroll
        for (int qq = 0; qq < 2; ++qq) {
            const int e = t + qq * 256;
            const int row = e >> 2, kg = (e & 3) * 8;
            *(u16x8*)(&lB[row * 40 + kg]) =
                *(const u16x8*)(Wbase + (size_t)(c0 + row) * 288 + k0 + kg);
        }
        __syncthreads();
        bf16x8 af[4], bfr[4];
#pragma unroll
        for (int i = 0; i < 4; ++i)
            af[i] = *(const bf16x8*)(&lA[(wm + i * 16 + l15) * 40 + q * 8]);
#pragma unroll
        for (int j = 0; j < 4; ++j)
            bfr[j] = *(const bf16x8*)(&lB[(wn + j * 16 + l15) * 40 + q * 8]);
#pragma unroll
        for (int i = 0; i < 4; ++i)
#pragma unroll
            for (int j = 0; j < 4; ++j)
                acc[i][j] = __builtin_amdgcn_mfma_f32_16x16x32_bf16(af[i], bfr[j], acc[i][j], 0, 0, 0);
        __syncthreads();
    }

#pragma unroll
    for (int j = 0; j < 4; ++j) {
        const int cg = c0 + wn + j * 16 + l15;
        const float bias = biasBase[cg];
        unsigned short* dst;
        int cd;
        if (cg < splitCol) { dst = outA; cd = cg; }
        else               { dst = outB; cd = cg - 2048; }
#pragma unroll
        for (int i = 0; i < 4; ++i)
#pragma unroll
            for (int r = 0; r < 4; ++r) {
                const int n = m0 + wm + i * 16 + q * 4 + r;
                dst[(size_t)n * 2048 + cd] = f2b(acc[i][j][r] + bias);
            }
    }
}

// ---------------- phi (in-place on [CH][2048] bf16), rows/block parameterized ----------------
// mode 0 (K): phi + colsum atomics (rows=8).  mode 1 (Q): phi*invden (rows=2).
__global__ __launch_bounds__(256) void phi_kernel(
    unsigned short* __restrict__ buf,
    const float* __restrict__ nsc,
    float* __restrict__ colsum,
    int mode, int rows)
{
    const int t = threadIdx.x;
    const int c8 = t * 8;
    const float c = fabsf(nsc[0]) + EPSF;
    float cs[8], csum[8];
#pragma unroll
    for (int e = 0; e < 8; ++e) csum[e] = 0.f;
    if (mode) {
#pragma unroll
        for (int e = 0; e < 8; ++e) cs[e] = colsum[c8 + e];
    }
    const int r0 = blockIdx.x * rows;
    for (int rr = 0; rr < rows; ++rr) {
        const int r = r0 + rr;
        u16x8 xv = *(const u16x8*)(buf + (size_t)r * 2048 + c8);
        float u[8];
        float s2 = 0.f, s4 = 0.f;
#pragma unroll
        for (int e = 0; e < 8; ++e) {
            float uu = fmaxf(b2f(xv[e]), 0.f) + EPSF;
            u[e] = uu;
            float q2 = uu * uu;
            s2 += q2;
            s4 += q2 * q2;
        }
#pragma unroll
        for (int m = 1; m <= 16; m <<= 1) {
            s2 += __shfl_xor(s2, m, 64);
            s4 += __shfl_xor(s4, m, 64);
        }
        const float sc = sqrtf(s2) / (c * sqrtf(s4));
        float ph[8];
#pragma unroll
        for (int e = 0; e < 8; ++e) ph[e] = u[e] * u[e] * sc;
        u16x8 ov;
        if (mode) {
            float den = 0.f;
#pragma unroll
            for (int e = 0; e < 8; ++e) den += ph[e] * cs[e];
#pragma unroll
            for (int m = 1; m <= 16; m <<= 1) den += __shfl_xor(den, m, 64);
            const float invd = 1.f / (den + EPSF);
#pragma unroll
            for (int e = 0; e < 8; ++e) ov[e] = f2b(ph[e] * invd);
        } else {
#pragma unroll
            for (int e = 0; e < 8; ++e) { ov[e] = f2b(ph[e]); csum[e] += ph[e]; }
        }
        *(u16x8*)(buf + (size_t)r * 2048 + c8) = ov;
    }
    if (!mode) {
#pragma unroll
        for (int e = 0; e < 8; ++e) atomicAdd(&colsum[c8 + e], csum[e]);
    }
}

// ---------------- ktv MFMA: ktv[h] += phiK_h^T @ vs_h ----------------
__global__ __launch_bounds__(256) void ktv_mfma(
    const unsigned short* __restrict__ phiK,
    const unsigned short* __restrict__ vsb,
    float* __restrict__ ktv)
{
    __shared__ __align__(16) unsigned short lAT[128 * 40];
    __shared__ __align__(16) unsigned short lBT[128 * 40];
    const int t = threadIdx.x;
    const int h = blockIdx.y;
    const int split = blockIdx.x >> 2;
    const int tile = blockIdx.x & 3;
    const int m0 = (tile >> 1) * 128, d0 = (tile & 1) * 128;
    const int chh = h * 256;
    const int lane = t & 63, w = t >> 6;
    const int wm = (w >> 1) * 64, wn = (w & 1) * 64;
    const int l15 = lane & 15, q8 = (lane >> 4) * 8;

    f32x4 acc[4][4] = {};
    const int nbeg = split * 512;
    for (int n0 = nbeg; n0 < nbeg + 512; n0 += 32) {
#pragma unroll
        for (int qq = 0; qq < 2; ++qq) {
            const int e = t + qq * 256;
            const int row = e >> 4, cg = (e & 15) * 8;
            u16x8 a = *(const u16x8*)(phiK + (size_t)(n0 + row) * 2048 + chh + m0 + cg);
            u16x8 b = *(const u16x8*)(vsb  + (size_t)(n0 + row) * 2048 + chh + d0 + cg);
#pragma unroll
            for (int j = 0; j < 8; ++j) {
                lAT[(cg + j) * 40 + row] = a[j];
                lBT[(cg + j) * 40 + row] = b[j];
            }
        }
        __syncthreads();
        bf16x8 af[4], bfr[4];
#pragma unroll
        for (int i = 0; i < 4; ++i)
            af[i] = *(const bf16x8*)(&lAT[(wm + i * 16 + l15) * 40 + q8]);
#pragma unroll
        for (int j = 0; j < 4; ++j)
            bfr[j] = *(const bf16x8*)(&lBT[(wn + j * 16 + l15) * 40 + q8]);
#pragma unroll
        for (int i = 0; i < 4; ++i)
#pragma unroll
            for (int j = 0; j < 4; ++j)
                acc[i][j] = __builtin_amdgcn_mfma_f32_16x16x32_bf16(af[i], bfr[j], acc[i][j], 0, 0, 0);
        __syncthreads();
    }
#pragma unroll
    for (int i = 0; i < 4; ++i)
#pragma unroll
        for (int j = 0; j < 4; ++j)
#pragma unroll
            for (int r = 0; r < 4; ++r) {
                const int m = m0 + wm + i * 16 + (lane >> 4) * 4 + r;
                const int d = d0 + wn + j * 16 + l15;
                atomicAdd(&ktv[((size_t)chh + m) * 256 + d], acc[i][j][r]);
            }
}

// ---------------- final MFMA GEMM 128x64 ----------------
__global__ __launch_bounds__(256) void final_mfma(
    const unsigned short* __restrict__ Abuf,
    const unsigned short* __restrict__ W2T,
    int kbeg, int kend, int accumulate,
    float* __restrict__ outp)
{
    __shared__ __align__(16) unsigned short lA[128 * 40];
    __shared__ __align__(16) unsigned short lB[64 * 40];
    const int t = threadIdx.x;
    const int n0 = blockIdx.x * 128;
    const int d0 = blockIdx.y * 64;
    const int lane = t & 63, w = t >> 6;
    const int wm = w * 32;
    const int l15 = lane & 15, q = lane >> 4;

    f32x4 acc[2][4] = {};
    for (int k0 = kbeg; k0 < kend; k0 += 32) {
#pragma unroll
        for (int qq = 0; qq < 2; ++qq) {
            const int e = t + qq * 256;
            const int row = e >> 2, kg = (e & 3) * 8;
            *(u16x8*)(&lA[row * 40 + kg]) =
                *(const u16x8*)(Abuf + (size_t)(n0 + row) * 2048 + ((k0 + kg) & 2047));
        }
        {
            const int row = t >> 2, kg = (t & 3) * 8;
            *(u16x8*)(&lB[row * 40 + kg]) =
                *(const u16x8*)(W2T + (size_t)(d0 + row) * 4096 + k0 + kg);
        }
        __syncthreads();
        bf16x8 af[2], bfr[4];
#pragma unroll
        for (int i = 0; i < 2; ++i)
            af[i] = *(const bf16x8*)(&lA[(wm + i * 16 + l15) * 40 + q * 8]);
#pragma unroll
        for (int j = 0; j < 4; ++j)
            bfr[j] = *(const bf16x8*)(&lB[(j * 16 + l15) * 40 + q * 8]);
#pragma unroll
        for (int i = 0; i < 2; ++i)
#pragma unroll
            for (int j = 0; j < 4; ++j)
                acc[i][j] = __builtin_amdgcn_mfma_f32_16x16x32_bf16(af[i], bfr[j], acc[i][j], 0, 0, 0);
        __syncthreads();
    }
#pragma unroll
    for (int i = 0; i < 2; ++i)
#pragma unroll
        for (int j = 0; j < 4; ++j)
#pragma unroll
            for (int r = 0; r < 4; ++r) {
                const int n = n0 + wm + i * 16 + q * 4 + r;
                const int d = d0 + j * 16 + l15;
                float* p = &outp[(size_t)n * 257 + 1 + d];
                if (accumulate) *p += acc[i][j][r];
                else            *p  = acc[i][j][r];
            }
}

// ---------------- W2T G part: G_h = vmw^T F_h^T ----------------
__global__ __launch_bounds__(256) void w2g_kernel(
    const float* __restrict__ vmw,
    const float* __restrict__ fw,
    unsigned short* __restrict__ W2T)
{
    const int t = threadIdx.x;
    const int h = blockIdx.x >> 3;
    const int i0 = (blockIdx.x & 7) * 32;

    __shared__ __align__(16) float xlds[16][40];
    __shared__ float wlds[256][17];

    float acc[32];
#pragma unroll
    for (int r = 0; r < 32; ++r) acc[r] = 0.f;

    const int ar = t >> 3;
    const int ak = (t & 7) * 2;
    const int wk = t & 15;
    const int wo = (t >> 4) * 16;

    for (int d0 = 0; d0 < 256; d0 += 16) {
        xlds[ak][ar]     = vmw[(size_t)(d0 + ak) * 256 + i0 + ar];
        xlds[ak + 1][ar] = vmw[(size_t)(d0 + ak + 1) * 256 + i0 + ar];
#pragma unroll
        for (int j = 0; j < 16; ++j)
            wlds[wo + j][wk] = fw[(size_t)(wo + j) * 2048 + h * 256 + d0 + wk];
        __syncthreads();
#pragma unroll
        for (int kk = 0; kk < 16; ++kk) {
            float bv = wlds[t][kk];
            const float4* xr = (const float4*)(&xlds[kk][0]);
#pragma unroll
            for (int g = 0; g < 8; ++g) {
                float4 xv = xr[g];
                acc[g * 4 + 0] = fmaf(xv.x, bv, acc[g * 4 + 0]);
                acc[g * 4 + 1] = fmaf(xv.y, bv, acc[g * 4 + 1]);
                acc[g * 4 + 2] = fmaf(xv.z, bv, acc[g * 4 + 2]);
                acc[g * 4 + 3] = fmaf(xv.w, bv, acc[g * 4 + 3]);
            }
        }
        __syncthreads();
    }
#pragma unroll
    for (int r = 0; r < 32; ++r)
        W2T[(size_t)t * 4096 + 2048 + h * 256 + i0 + r] = f2b(acc[r]);
}

// ---------------- bias2[o] = fb[o] + sum_j vmb[j&255]*fw[o*2048+j] ----------------
__global__ __launch_bounds__(256) void bias2_kernel(
    const float* __restrict__ vmb, const float* __restrict__ fw,
    const float* __restrict__ fb, float* __restrict__ bias2)
{
    const int o = blockIdx.x;
    const int t = threadIdx.x;
    float s = 0.f;
#pragma unroll
    for (int i = 0; i < 8; ++i)
        s += fw[(size_t)o * 2048 + t + i * 256];
    s *= vmb[t];
#pragma unroll
    for (int off = 32; off > 0; off >>= 1) s += __shfl_down(s, off, 64);
    __shared__ float r4[4];
    if ((t & 63) == 0) r4[t >> 6] = s;
    __syncthreads();
    if (t == 0) bias2[o] = fb[o] + r4[0] + r4[1] + r4[2] + r4[3];
}

// ---------------- W2T upper = ktv_h @ F_h^T (bf16) ----------------
__global__ __launch_bounds__(256) void w2u_kernel(
    const float* __restrict__ ktv,
    const float* __restrict__ fw,
    unsigned short* __restrict__ W2T)
{
    const int t = threadIdx.x;
    const int h = blockIdx.x >> 3;
    const int m0 = (blockIdx.x & 7) * 32;

    __shared__ __align__(16) float xlds[16][40];
    __shared__ float wlds[256][17];

    float acc[32];
#pragma unroll
    for (int r = 0; r < 32; ++r) acc[r] = 0.f;

    const int ar = t >> 3;
    const int ak = (t & 7) * 2;
    const int wk = t & 15;
    const int wo = (t >> 4) * 16;

    for (int d0 = 0; d0 < 256; d0 += 16) {
        {
            const float* src = ktv + (size_t)(h * 256 + m0 + ar) * 256 + d0 + ak;
            xlds[ak][ar]     = src[0];
            xlds[ak + 1][ar] = src[1];
        }
#pragma unroll
        for (int j = 0; j < 16; ++j)
            wlds[wo + j][wk] = fw[(size_t)(wo + j) * 2048 + h * 256 + d0 + wk];
        __syncthreads();
#pragma unroll
        for (int kk = 0; kk < 16; ++kk) {
            float bv = wlds[t][kk];
            const float4* xr = (const float4*)(&xlds[kk][0]);
#pragma unroll
            for (int g = 0; g < 8; ++g) {
                float4 xv = xr[g];
                acc[g * 4 + 0] = fmaf(xv.x, bv, acc[g * 4 + 0]);
                acc[g * 4 + 1] = fmaf(xv.y, bv, acc[g * 4 + 1]);
                acc[g * 4 + 2] = fmaf(xv.z, bv, acc[g * 4 + 2]);
                acc[g * 4 + 3] = fmaf(xv.w, bv, acc[g * 4 + 3]);
            }
        }
        __syncthreads();
    }
#pragma unroll
    for (int r = 0; r < 32; ++r)
        W2T[(size_t)t * 4096 + h * 256 + m0 + r] = f2b(acc[r]);
}

// ---------------- epilogue: bias + Lorentz lift ----------------
__global__ __launch_bounds__(256) void lift_kernel(
    const float* __restrict__ bias2, float* __restrict__ outp)
{
    const int t = threadIdx.x;
    const int lane = t & 63;
    const int w = t >> 6;
    const int n0 = blockIdx.x * 64 + w * 16;
    float b[4];
#pragma unroll
    for (int j = 0; j < 4; ++j) b[j] = bias2[lane + j * 64];
    for (int r = 0; r < 16; ++r) {
        float* row = outp + (size_t)(n0 + r) * 257;
        float v[4];
        float s = 0.f;
#pragma unroll
        for (int j = 0; j < 4; ++j) {
            v[j] = row[1 + lane + j * 64] + b[j];
            s = fmaf(v[j], v[j], s);
        }
#pragma unroll
        for (int off = 32; off > 0; off >>= 1) s += __shfl_down(s, off, 64);
#pragma unroll
        for (int j = 0; j < 4; ++j) row[1 + lane + j * 64] = v[j];
        if (lane == 0) row[0] = sqrtf(s + 1.0f);
    }
}

extern "C" void kernel_launch(void* const* d_in, const int* in_sizes, int n_in,
                              void* d_out, int out_size, void* d_ws, size_t ws_size,
                              hipStream_t stream)
{
    const float* xq  = (const float*)d_in[0];
    const float* xs  = (const float*)d_in[1];
    const float* Wq  = (const float*)d_in[2];
    const float* Bq  = (const float*)d_in[3];
    const float* Wk  = (const float*)d_in[4];
    const float* Bk  = (const float*)d_in[5];
    const float* Wv  = (const float*)d_in[6];
    const float* Bv  = (const float*)d_in[7];
    const float* nsc = (const float*)d_in[8];
    const float* vmw = (const float*)d_in[9];
    const float* vmb = (const float*)d_in[10];
    const float* fw  = (const float*)d_in[11];
    const float* fb  = (const float*)d_in[12];
    float* outp = (float*)d_out;

    char* ws = (char*)d_ws;
    float* ktv          = (float*)(ws + 0);                // 2,097,152
    float* colsum       = (float*)(ws + 2097152);          //     8,192
    float* bias2        = (float*)(ws + 2105344);          //     1,024
    float* biasAll      = (float*)(ws + 2106368);          //    24,576
    unsigned short* W2T = (unsigned short*)(ws + 2130944); // 2,097,152
    unsigned short* Wbf = (unsigned short*)(ws + 4228096); // 3,538,944
    const size_t fixedBytes = 7767040;

    int CH = 2048;
    if (ws_size >= fixedBytes + (size_t)8192 * 8192) CH = 8192;
    else if (ws_size >= fixedBytes + (size_t)4096 * 8192) CH = 4096;
    const int NCHK = 32768 / CH;
    unsigned short* phibuf = (unsigned short*)(ws + fixedBytes);
    unsigned short* vsbuf  = (unsigned short*)(ws + fixedBytes + (size_t)CH * 4096);

    zero_kernel<<<dim3(2056), 256, 0, stream>>>(ktv, 526336);
    wconv_kernel<<<dim3(6168), 256, 0, stream>>>(Wq, Wk, Wv, Bq, Bk, Bv, Wbf, biasAll);
    w2g_kernel<<<dim3(64), 256, 0, stream>>>(vmw, fw, W2T);
    bias2_kernel<<<dim3(256), 256, 0, stream>>>(vmb, fw, fb, bias2);

    // Pass A: K/V chunks -> phiK, colsum, ktv, out = vs @ G
    for (int c = 0; c < NCHK; ++c) {
        const float* xs_c = xs + (size_t)c * CH * 257;
        float* out_c = outp + (size_t)c * CH * 257;
        proj_mfma<<<dim3(CH / 128, 32), 256, 0, stream>>>(
            xs_c, Wbf + (size_t)2048 * 288, biasAll + 2048, phibuf, vsbuf, 2048);
        phi_kernel<<<dim3(CH / 8), 256, 0, stream>>>(phibuf, nsc, colsum, 0, 8);
        ktv_mfma<<<dim3((CH / 512) * 4, 8), 256, 0, stream>>>(phibuf, vsbuf, ktv);
        final_mfma<<<dim3(CH / 128, 4), 256, 0, stream>>>(vsbuf, W2T, 2048, 4096, 0, out_c);
    }

    // ktv-dependent weights
    w2u_kernel<<<dim3(64), 256, 0, stream>>>(ktv, fw, W2T);

    // Pass B: Q chunks -> phiQ*invden, out += phiQs @ W2u
    for (int c = 0; c < NCHK; ++c) {
        const float* xq_c = xq + (size_t)c * CH * 257;
        float* out_c = outp + (size_t)c * CH * 257;
        proj_mfma<<<dim3(CH / 128, 16), 256, 0, stream>>>(
            xq_c, Wbf, biasAll, phibuf, phibuf, 4096);
        phi_kernel<<<dim3(CH / 2), 256, 0, stream>>>(phibuf, nsc, colsum, 1, 2);
        final_mfma<<<dim3(CH / 128, 4), 256, 0, stream>>>(phibuf, W2T, 0, 2048, 1, out_c);
    }

    // bias + Lorentz lift
    lift_kernel<<<dim3(512), 256, 0, stream>>>(bias2, outp);
}

// Round 7
// 1547.048 us; speedup vs baseline: 1.3726x; 1.3726x over previous
//
#include <hip/hip_runtime.h>
#include <hip/hip_bf16.h>

// DHHT round 7: phi latency fix.
//  - phi_kernel: batch-load 8 rows into regs BEFORE any store (in-place RMW
//    self-aliasing serialized rows in r5/r6 -> ~everything latency-bound).
//  - colsum: 8-way replicated accumulators + merge kernel (atomic ping-pong fix).
//  - grids/tiles otherwise as round 5 (1766us config).
// W2T bf16 [256][4096]: cols 0..2047 = W2u (ktv@F^T), 2048..4095 = G.

#define EPSF 1e-6f

typedef __attribute__((ext_vector_type(8))) short bf16x8;
typedef __attribute__((ext_vector_type(8))) unsigned short u16x8;
typedef __attribute__((ext_vector_type(4))) float f32x4;
typedef float f32x4a __attribute__((ext_vector_type(4), aligned(4)));

__device__ __forceinline__ float b2f(unsigned short u) {
    union { unsigned int i; float f; } c;
    c.i = ((unsigned int)u) << 16;
    return c.f;
}
__device__ __forceinline__ unsigned short f2b(float f) {
    __hip_bfloat16 h = __float2bfloat16(f);
    union { __hip_bfloat16 h; unsigned short u; } c;
    c.h = h;
    return c.u;
}

__global__ void zero_kernel(float* __restrict__ p, int n) {
    int i = blockIdx.x * 256 + threadIdx.x;
    if (i < n) p[i] = 0.f;
}

// ---------------- weight convert: Wbf [6144][288] bf16 + biasAll[6144] ----------------
__global__ __launch_bounds__(256) void wconv_kernel(
    const float* __restrict__ Wq, const float* __restrict__ Wk, const float* __restrict__ Wv,
    const float* __restrict__ Bq, const float* __restrict__ Bk, const float* __restrict__ Bv,
    unsigned short* __restrict__ Wbf, float* __restrict__ biasAll)
{
    const int t = threadIdx.x;
    const int b = blockIdx.x;
    if (b < 6144) {
        const int mat = b >> 11, lr = b & 2047;
        const float* Ws = (mat == 0 ? Wq : mat == 1 ? Wk : Wv) + (size_t)lr * 257;
        Wbf[(size_t)b * 288 + t] = f2b(Ws[t]);
        if (t < 32) {
            float v = (t == 0) ? Ws[256] : 0.f;
            Wbf[(size_t)b * 288 + 256 + t] = f2b(v);
        }
    } else {
        const int e = (b - 6144) * 256 + t;
        const int mat = e >> 11, r = e & 2047;
        biasAll[e] = (mat == 0 ? Bq : mat == 1 ? Bk : Bv)[r];
    }
}

// ---------------- projection MFMA GEMM: X fp32 [rows][257] @ Wbf[cols][288]^T ----------------
__global__ __launch_bounds__(256) void proj_mfma(
    const float* __restrict__ X,
    const unsigned short* __restrict__ Wbase,
    const float* __restrict__ biasBase,
    unsigned short* __restrict__ outA,
    unsigned short* __restrict__ outB,
    int splitCol)
{
    __shared__ __align__(16) unsigned short lA[128 * 40];
    __shared__ __align__(16) unsigned short lB[128 * 40];
    const int t = threadIdx.x;
    const int m0 = blockIdx.x * 128;
    const int c0 = blockIdx.y * 128;
    const int lane = t & 63, w = t >> 6;
    const int wm = (w >> 1) * 64, wn = (w & 1) * 64;
    const int l15 = lane & 15, q = lane >> 4;

    f32x4 acc[4][4] = {};

    for (int ks = 0; ks < 9; ++ks) {
        const int k0 = ks * 32;
        if (ks < 8) {
#pragma unroll
            for (int qq = 0; qq < 4; ++qq) {
                const int e = t + qq * 256;
                const int row = e >> 3, kg = (e & 7) * 4;
                f32x4a xv = *(const f32x4a*)(X + (size_t)(m0 + row) * 257 + k0 + kg);
                unsigned short* d = &lA[row * 40 + kg];
                d[0] = f2b(xv[0]); d[1] = f2b(xv[1]);
                d[2] = f2b(xv[2]); d[3] = f2b(xv[3]);
            }
        } else {
#pragma unroll
            for (int qq = 0; qq < 2; ++qq) {
                const int e = t + qq * 256;
                const int row = e >> 2, part = e & 3;
                u16x8 z = {};
                if (part == 0) z[0] = f2b(X[(size_t)(m0 + row) * 257 + 256]);
                *(u16x8*)(&lA[row * 40 + part * 8]) = z;
            }
        }
#pragma unroll
        for (int qq = 0; qq < 2; ++qq) {
            const int e = t + qq * 256;
            const int row = e >> 2, kg = (e & 3) * 8;
            *(u16x8*)(&lB[row * 40 + kg]) =
                *(const u16x8*)(Wbase + (size_t)(c0 + row) * 288 + k0 + kg);
        }
        __syncthreads();
        bf16x8 af[4], bfr[4];
#pragma unroll
        for (int i = 0; i < 4; ++i)
            af[i] = *(const bf16x8*)(&lA[(wm + i * 16 + l15) * 40 + q * 8]);
#pragma unroll
        for (int j = 0; j < 4; ++j)
            bfr[j] = *(const bf16x8*)(&lB[(wn + j * 16 + l15) * 40 + q * 8]);
#pragma unroll
        for (int i = 0; i < 4; ++i)
#pragma unroll
            for (int j = 0; j < 4; ++j)
                acc[i][j] = __builtin_amdgcn_mfma_f32_16x16x32_bf16(af[i], bfr[j], acc[i][j], 0, 0, 0);
        __syncthreads();
    }

#pragma unroll
    for (int j = 0; j < 4; ++j) {
        const int cg = c0 + wn + j * 16 + l15;
        const float bias = biasBase[cg];
        unsigned short* dst;
        int cd;
        if (cg < splitCol) { dst = outA; cd = cg; }
        else               { dst = outB; cd = cg - 2048; }
#pragma unroll
        for (int i = 0; i < 4; ++i)
#pragma unroll
            for (int r = 0; r < 4; ++r) {
                const int n = m0 + wm + i * 16 + q * 4 + r;
                dst[(size_t)n * 2048 + cd] = f2b(acc[i][j][r] + bias);
            }
    }
}

// ---------------- phi (in-place on [CH][2048] bf16), batch-loaded 8 rows ----------------
// mode 0 (K): phi + colsum replica atomics.  mode 1 (Q): phi * invden.
__global__ __launch_bounds__(256) void phi_kernel(
    unsigned short* __restrict__ buf,
    const float* __restrict__ nsc,
    const float* __restrict__ colsum_in,   // merged colsum (Q mode)
    float* __restrict__ colsum_rep,        // replica base (K mode)
    int mode)
{
    const int t = threadIdx.x;
    const int c8 = t * 8;
    const float c = fabsf(nsc[0]) + EPSF;
    const int r0 = blockIdx.x * 8;

    // batch load: all 8 row-slices in flight before any compute/store
    u16x8 xv[8];
#pragma unroll
    for (int rr = 0; rr < 8; ++rr)
        xv[rr] = *(const u16x8*)(buf + (size_t)(r0 + rr) * 2048 + c8);

    float cs[8];
    if (mode) {
#pragma unroll
        for (int e = 0; e < 8; ++e) cs[e] = colsum_in[c8 + e];
    }

    // per-row norms (independent chains -> ILP across rows)
    float s2[8], s4[8];
#pragma unroll
    for (int rr = 0; rr < 8; ++rr) {
        float a2 = 0.f, a4 = 0.f;
#pragma unroll
        for (int e = 0; e < 8; ++e) {
            float uu = fmaxf(b2f(xv[rr][e]), 0.f) + EPSF;
            float q2 = uu * uu;
            a2 += q2;
            a4 += q2 * q2;
        }
        s2[rr] = a2; s4[rr] = a4;
    }
#pragma unroll
    for (int m = 1; m <= 16; m <<= 1) {
#pragma unroll
        for (int rr = 0; rr < 8; ++rr) {
            s2[rr] += __shfl_xor(s2[rr], m, 64);
            s4[rr] += __shfl_xor(s4[rr], m, 64);
        }
    }

    float csum[8];
#pragma unroll
    for (int e = 0; e < 8; ++e) csum[e] = 0.f;

#pragma unroll
    for (int rr = 0; rr < 8; ++rr) {
        const float sc = sqrtf(s2[rr]) / (c * sqrtf(s4[rr]));
        float ph[8];
#pragma unroll
        for (int e = 0; e < 8; ++e) {
            float uu = fmaxf(b2f(xv[rr][e]), 0.f) + EPSF;
            ph[e] = uu * uu * sc;
        }
        u16x8 ov;
        if (mode) {
            float den = 0.f;
#pragma unroll
            for (int e = 0; e < 8; ++e) den += ph[e] * cs[e];
#pragma unroll
            for (int m = 1; m <= 16; m <<= 1) den += __shfl_xor(den, m, 64);
            const float invd = 1.f / (den + EPSF);
#pragma unroll
            for (int e = 0; e < 8; ++e) ov[e] = f2b(ph[e] * invd);
        } else {
#pragma unroll
            for (int e = 0; e < 8; ++e) { ov[e] = f2b(ph[e]); csum[e] += ph[e]; }
        }
        *(u16x8*)(buf + (size_t)(r0 + rr) * 2048 + c8) = ov;
    }
    if (!mode) {
        float* dst = colsum_rep + (size_t)(blockIdx.x & 7) * 2048 + c8;
#pragma unroll
        for (int e = 0; e < 8; ++e) atomicAdd(&dst[e], csum[e]);
    }
}

// ---------------- merge colsum replicas: out[c] = sum_r rep[r][c] ----------------
__global__ __launch_bounds__(256) void merge_colsum(
    const float* __restrict__ rep, float* __restrict__ out)
{
    const int cidx = blockIdx.x * 256 + threadIdx.x;  // 0..2047
    float s = 0.f;
#pragma unroll
    for (int r = 0; r < 8; ++r) s += rep[(size_t)r * 2048 + cidx];
    out[cidx] = s;
}

// ---------------- ktv MFMA: ktv[h] += phiK_h^T @ vs_h ----------------
__global__ __launch_bounds__(256) void ktv_mfma(
    const unsigned short* __restrict__ phiK,
    const unsigned short* __restrict__ vsb,
    float* __restrict__ ktv)
{
    __shared__ __align__(16) unsigned short lAT[128 * 40];
    __shared__ __align__(16) unsigned short lBT[128 * 40];
    const int t = threadIdx.x;
    const int h = blockIdx.y;
    const int split = blockIdx.x >> 2;
    const int tile = blockIdx.x & 3;
    const int m0 = (tile >> 1) * 128, d0 = (tile & 1) * 128;
    const int chh = h * 256;
    const int lane = t & 63, w = t >> 6;
    const int wm = (w >> 1) * 64, wn = (w & 1) * 64;
    const int l15 = lane & 15, q8 = (lane >> 4) * 8;

    f32x4 acc[4][4] = {};
    const int nbeg = split * 512;
    for (int n0 = nbeg; n0 < nbeg + 512; n0 += 32) {
#pragma unroll
        for (int qq = 0; qq < 2; ++qq) {
            const int e = t + qq * 256;
            const int row = e >> 4, cg = (e & 15) * 8;
            u16x8 a = *(const u16x8*)(phiK + (size_t)(n0 + row) * 2048 + chh + m0 + cg);
            u16x8 b = *(const u16x8*)(vsb  + (size_t)(n0 + row) * 2048 + chh + d0 + cg);
#pragma unroll
            for (int j = 0; j < 8; ++j) {
                lAT[(cg + j) * 40 + row] = a[j];
                lBT[(cg + j) * 40 + row] = b[j];
            }
        }
        __syncthreads();
        bf16x8 af[4], bfr[4];
#pragma unroll
        for (int i = 0; i < 4; ++i)
            af[i] = *(const bf16x8*)(&lAT[(wm + i * 16 + l15) * 40 + q8]);
#pragma unroll
        for (int j = 0; j < 4; ++j)
            bfr[j] = *(const bf16x8*)(&lBT[(wn + j * 16 + l15) * 40 + q8]);
#pragma unroll
        for (int i = 0; i < 4; ++i)
#pragma unroll
            for (int j = 0; j < 4; ++j)
                acc[i][j] = __builtin_amdgcn_mfma_f32_16x16x32_bf16(af[i], bfr[j], acc[i][j], 0, 0, 0);
        __syncthreads();
    }
#pragma unroll
    for (int i = 0; i < 4; ++i)
#pragma unroll
        for (int j = 0; j < 4; ++j)
#pragma unroll
            for (int r = 0; r < 4; ++r) {
                const int m = m0 + wm + i * 16 + (lane >> 4) * 4 + r;
                const int d = d0 + wn + j * 16 + l15;
                atomicAdd(&ktv[((size_t)chh + m) * 256 + d], acc[i][j][r]);
            }
}

// ---------------- final MFMA GEMM 128x64 ----------------
__global__ __launch_bounds__(256) void final_mfma(
    const unsigned short* __restrict__ Abuf,
    const unsigned short* __restrict__ W2T,
    int kbeg, int kend, int accumulate,
    float* __restrict__ outp)
{
    __shared__ __align__(16) unsigned short lA[128 * 40];
    __shared__ __align__(16) unsigned short lB[64 * 40];
    const int t = threadIdx.x;
    const int n0 = blockIdx.x * 128;
    const int d0 = blockIdx.y * 64;
    const int lane = t & 63, w = t >> 6;
    const int wm = w * 32;
    const int l15 = lane & 15, q = lane >> 4;

    f32x4 acc[2][4] = {};
    for (int k0 = kbeg; k0 < kend; k0 += 32) {
#pragma unroll
        for (int qq = 0; qq < 2; ++qq) {
            const int e = t + qq * 256;
            const int row = e >> 2, kg = (e & 3) * 8;
            *(u16x8*)(&lA[row * 40 + kg]) =
                *(const u16x8*)(Abuf + (size_t)(n0 + row) * 2048 + ((k0 + kg) & 2047));
        }
        {
            const int row = t >> 2, kg = (t & 3) * 8;
            *(u16x8*)(&lB[row * 40 + kg]) =
                *(const u16x8*)(W2T + (size_t)(d0 + row) * 4096 + k0 + kg);
        }
        __syncthreads();
        bf16x8 af[2], bfr[4];
#pragma unroll
        for (int i = 0; i < 2; ++i)
            af[i] = *(const bf16x8*)(&lA[(wm + i * 16 + l15) * 40 + q * 8]);
#pragma unroll
        for (int j = 0; j < 4; ++j)
            bfr[j] = *(const bf16x8*)(&lB[(j * 16 + l15) * 40 + q * 8]);
#pragma unroll
        for (int i = 0; i < 2; ++i)
#pragma unroll
            for (int j = 0; j < 4; ++j)
                acc[i][j] = __builtin_amdgcn_mfma_f32_16x16x32_bf16(af[i], bfr[j], acc[i][j], 0, 0, 0);
        __syncthreads();
    }
#pragma unroll
    for (int i = 0; i < 2; ++i)
#pragma unroll
        for (int j = 0; j < 4; ++j)
#pragma unroll
            for (int r = 0; r < 4; ++r) {
                const int n = n0 + wm + i * 16 + q * 4 + r;
                const int d = d0 + j * 16 + l15;
                float* p = &outp[(size_t)n * 257 + 1 + d];
                if (accumulate) *p += acc[i][j][r];
                else            *p  = acc[i][j][r];
            }
}

// ---------------- W2T G part: G_h = vmw^T F_h^T ----------------
__global__ __launch_bounds__(256) void w2g_kernel(
    const float* __restrict__ vmw,
    const float* __restrict__ fw,
    unsigned short* __restrict__ W2T)
{
    const int t = threadIdx.x;
    const int h = blockIdx.x >> 3;
    const int i0 = (blockIdx.x & 7) * 32;

    __shared__ __align__(16) float xlds[16][40];
    __shared__ float wlds[256][17];

    float acc[32];
#pragma unroll
    for (int r = 0; r < 32; ++r) acc[r] = 0.f;

    const int ar = t >> 3;
    const int ak = (t & 7) * 2;
    const int wk = t & 15;
    const int wo = (t >> 4) * 16;

    for (int d0 = 0; d0 < 256; d0 += 16) {
        xlds[ak][ar]     = vmw[(size_t)(d0 + ak) * 256 + i0 + ar];
        xlds[ak + 1][ar] = vmw[(size_t)(d0 + ak + 1) * 256 + i0 + ar];
#pragma unroll
        for (int j = 0; j < 16; ++j)
            wlds[wo + j][wk] = fw[(size_t)(wo + j) * 2048 + h * 256 + d0 + wk];
        __syncthreads();
#pragma unroll
        for (int kk = 0; kk < 16; ++kk) {
            float bv = wlds[t][kk];
            const float4* xr = (const float4*)(&xlds[kk][0]);
#pragma unroll
            for (int g = 0; g < 8; ++g) {
                float4 xv = xr[g];
                acc[g * 4 + 0] = fmaf(xv.x, bv, acc[g * 4 + 0]);
                acc[g * 4 + 1] = fmaf(xv.y, bv, acc[g * 4 + 1]);
                acc[g * 4 + 2] = fmaf(xv.z, bv, acc[g * 4 + 2]);
                acc[g * 4 + 3] = fmaf(xv.w, bv, acc[g * 4 + 3]);
            }
        }
        __syncthreads();
    }
#pragma unroll
    for (int r = 0; r < 32; ++r)
        W2T[(size_t)t * 4096 + 2048 + h * 256 + i0 + r] = f2b(acc[r]);
}

// ---------------- bias2[o] = fb[o] + sum_j vmb[j&255]*fw[o*2048+j] ----------------
__global__ __launch_bounds__(256) void bias2_kernel(
    const float* __restrict__ vmb, const float* __restrict__ fw,
    const float* __restrict__ fb, float* __restrict__ bias2)
{
    const int o = blockIdx.x;
    const int t = threadIdx.x;
    float s = 0.f;
#pragma unroll
    for (int i = 0; i < 8; ++i)
        s += fw[(size_t)o * 2048 + t + i * 256];
    s *= vmb[t];
#pragma unroll
    for (int off = 32; off > 0; off >>= 1) s += __shfl_down(s, off, 64);
    __shared__ float r4[4];
    if ((t & 63) == 0) r4[t >> 6] = s;
    __syncthreads();
    if (t == 0) bias2[o] = fb[o] + r4[0] + r4[1] + r4[2] + r4[3];
}

// ---------------- W2T upper = ktv_h @ F_h^T (bf16) ----------------
__global__ __launch_bounds__(256) void w2u_kernel(
    const float* __restrict__ ktv,
    const float* __restrict__ fw,
    unsigned short* __restrict__ W2T)
{
    const int t = threadIdx.x;
    const int h = blockIdx.x >> 3;
    const int m0 = (blockIdx.x & 7) * 32;

    __shared__ __align__(16) float xlds[16][40];
    __shared__ float wlds[256][17];

    float acc[32];
#pragma unroll
    for (int r = 0; r < 32; ++r) acc[r] = 0.f;

    const int ar = t >> 3;
    const int ak = (t & 7) * 2;
    const int wk = t & 15;
    const int wo = (t >> 4) * 16;

    for (int d0 = 0; d0 < 256; d0 += 16) {
        {
            const float* src = ktv + (size_t)(h * 256 + m0 + ar) * 256 + d0 + ak;
            xlds[ak][ar]     = src[0];
            xlds[ak + 1][ar] = src[1];
        }
#pragma unroll
        for (int j = 0; j < 16; ++j)
            wlds[wo + j][wk] = fw[(size_t)(wo + j) * 2048 + h * 256 + d0 + wk];
        __syncthreads();
#pragma unroll
        for (int kk = 0; kk < 16; ++kk) {
            float bv = wlds[t][kk];
            const float4* xr = (const float4*)(&xlds[kk][0]);
#pragma unroll
            for (int g = 0; g < 8; ++g) {
                float4 xv = xr[g];
                acc[g * 4 + 0] = fmaf(xv.x, bv, acc[g * 4 + 0]);
                acc[g * 4 + 1] = fmaf(xv.y, bv, acc[g * 4 + 1]);
                acc[g * 4 + 2] = fmaf(xv.z, bv, acc[g * 4 + 2]);
                acc[g * 4 + 3] = fmaf(xv.w, bv, acc[g * 4 + 3]);
            }
        }
        __syncthreads();
    }
#pragma unroll
    for (int r = 0; r < 32; ++r)
        W2T[(size_t)t * 4096 + h * 256 + m0 + r] = f2b(acc[r]);
}

// ---------------- epilogue: bias + Lorentz lift ----------------
__global__ __launch_bounds__(256) void lift_kernel(
    const float* __restrict__ bias2, float* __restrict__ outp)
{
    const int t = threadIdx.x;
    const int lane = t & 63;
    const int w = t >> 6;
    const int n0 = blockIdx.x * 64 + w * 16;
    float b[4];
#pragma unroll
    for (int j = 0; j < 4; ++j) b[j] = bias2[lane + j * 64];
    for (int r = 0; r < 16; ++r) {
        float* row = outp + (size_t)(n0 + r) * 257;
        float v[4];
        float s = 0.f;
#pragma unroll
        for (int j = 0; j < 4; ++j) {
            v[j] = row[1 + lane + j * 64] + b[j];
            s = fmaf(v[j], v[j], s);
        }
#pragma unroll
        for (int off = 32; off > 0; off >>= 1) s += __shfl_down(s, off, 64);
#pragma unroll
        for (int j = 0; j < 4; ++j) row[1 + lane + j * 64] = v[j];
        if (lane == 0) row[0] = sqrtf(s + 1.0f);
    }
}

extern "C" void kernel_launch(void* const* d_in, const int* in_sizes, int n_in,
                              void* d_out, int out_size, void* d_ws, size_t ws_size,
                              hipStream_t stream)
{
    const float* xq  = (const float*)d_in[0];
    const float* xs  = (const float*)d_in[1];
    const float* Wq  = (const float*)d_in[2];
    const float* Bq  = (const float*)d_in[3];
    const float* Wk  = (const float*)d_in[4];
    const float* Bk  = (const float*)d_in[5];
    const float* Wv  = (const float*)d_in[6];
    const float* Bv  = (const float*)d_in[7];
    const float* nsc = (const float*)d_in[8];
    const float* vmw = (const float*)d_in[9];
    const float* vmb = (const float*)d_in[10];
    const float* fw  = (const float*)d_in[11];
    const float* fb  = (const float*)d_in[12];
    float* outp = (float*)d_out;

    char* ws = (char*)d_ws;
    float* ktv          = (float*)(ws + 0);                // 2,097,152
    float* colrep       = (float*)(ws + 2097152);          //    65,536 (8x2048)
    float* colsum       = (float*)(ws + 2162688);          //     8,192 (merged)
    float* bias2        = (float*)(ws + 2170880);          //     1,024
    float* biasAll      = (float*)(ws + 2171904);          //    24,576
    unsigned short* W2T = (unsigned short*)(ws + 2196480); // 2,097,152
    unsigned short* Wbf = (unsigned short*)(ws + 4293632); // 3,538,944
    const size_t fixedBytes = 7832576;

    int CH = 2048;
    if (ws_size >= fixedBytes + (size_t)8192 * 8192) CH = 8192;
    else if (ws_size >= fixedBytes + (size_t)4096 * 8192) CH = 4096;
    const int NCHK = 32768 / CH;
    unsigned short* phibuf = (unsigned short*)(ws + fixedBytes);
    unsigned short* vsbuf  = (unsigned short*)(ws + fixedBytes + (size_t)CH * 4096);

    // zero ktv + colrep (contiguous 540672 floats)
    zero_kernel<<<dim3(2112), 256, 0, stream>>>(ktv, 540672);
    wconv_kernel<<<dim3(6168), 256, 0, stream>>>(Wq, Wk, Wv, Bq, Bk, Bv, Wbf, biasAll);
    w2g_kernel<<<dim3(64), 256, 0, stream>>>(vmw, fw, W2T);
    bias2_kernel<<<dim3(256), 256, 0, stream>>>(vmb, fw, fb, bias2);

    // Pass A: K/V chunks -> phiK, colsum replicas, ktv, out = vs @ G
    for (int c = 0; c < NCHK; ++c) {
        const float* xs_c = xs + (size_t)c * CH * 257;
        float* out_c = outp + (size_t)c * CH * 257;
        proj_mfma<<<dim3(CH / 128, 32), 256, 0, stream>>>(
            xs_c, Wbf + (size_t)2048 * 288, biasAll + 2048, phibuf, vsbuf, 2048);
        phi_kernel<<<dim3(CH / 8), 256, 0, stream>>>(phibuf, nsc, colsum, colrep, 0);
        ktv_mfma<<<dim3((CH / 512) * 4, 8), 256, 0, stream>>>(phibuf, vsbuf, ktv);
        final_mfma<<<dim3(CH / 128, 4), 256, 0, stream>>>(vsbuf, W2T, 2048, 4096, 0, out_c);
    }

    // merge colsum replicas; ktv-dependent weights
    merge_colsum<<<dim3(8), 256, 0, stream>>>(colrep, colsum);
    w2u_kernel<<<dim3(64), 256, 0, stream>>>(ktv, fw, W2T);

    // Pass B: Q chunks -> phiQ*invden, out += phiQs @ W2u
    for (int c = 0; c < NCHK; ++c) {
        const float* xq_c = xq + (size_t)c * CH * 257;
        float* out_c = outp + (size_t)c * CH * 257;
        proj_mfma<<<dim3(CH / 128, 16), 256, 0, stream>>>(
            xq_c, Wbf, biasAll, phibuf, phibuf, 4096);
        phi_kernel<<<dim3(CH / 8), 256, 0, stream>>>(phibuf, nsc, colsum, colrep, 1);
        final_mfma<<<dim3(CH / 128, 4), 256, 0, stream>>>(phibuf, W2T, 0, 2048, 1, out_c);
    }

    // bias + Lorentz lift
    lift_kernel<<<dim3(512), 256, 0, stream>>>(bias2, outp);
}